// Round 3
// baseline (1803.743 us; speedup 1.0000x reference)
//
#include <hip/hip_runtime.h>

typedef _Float16 h8 __attribute__((ext_vector_type(8)));
typedef _Float16 h4 __attribute__((ext_vector_type(4)));
typedef float f4 __attribute__((ext_vector_type(4)));

#define SEQ_LEN 50
#define HID 64
#define HS 72  // halves per h row: 144B pitch; 16B-aligned b128 reads

#if __has_builtin(__builtin_amdgcn_exp2f)
#define EXP2(x) __builtin_amdgcn_exp2f(x)
#else
extern "C" __device__ float __ocml_native_exp2_f32(float);
#define EXP2(x) __ocml_native_exp2_f32(x)
#endif
#define RCP(x) __builtin_amdgcn_rcpf(x)

#if __has_builtin(__builtin_amdgcn_mfma_f32_16x16x16f16)
typedef h4 axv_t;
#define XMFMA(A,B,C) __builtin_amdgcn_mfma_f32_16x16x16f16(A, B, C, 0, 0, 0)
#else
typedef h8 axv_t;
#define XMFMA(A,B,C) __builtin_amdgcn_mfma_f32_16x16x32_f16(A, B, C, 0, 0, 0)
#endif
#define WMFMA(A,B,C) __builtin_amdgcn_mfma_f32_16x16x32_f16(A, B, C, 0, 0, 0)

#define LOG2E  1.442695041f
#define LOG2E2 2.885390082f

// R9: two independent 16-seq tiles per 2-wave block, expressed as a
// compile-time-unrolled tb loop around R1's verbatim verified code (R2's
// hand-duplicated variant failed; this removes the typo class), and
// __launch_bounds__(128,2) so ~170 live VGPRs fit with no spills (R2 was
// over the (128,3) 168-cap -> possible spill-path miscompilation).
// R1 evidence driving the 2-tile design: cutting issue work left duration
// unchanged -> latency-bound, all pipes <65% busy. Weights (Aw/Ax) shared
// across tiles; only per-tile state (Bh/acc/c) duplicates; barriers per
// sequence-step halve; ~4 independent chains/SIMD vs 2.65.
//
// Orientation per tile (R7, verified): gates^T = W_ext @ [h; x; 1].
// Wave w owns units 32w..32w+31. D layout: col=lane&15 = seq,
// row=quad*4+r = unit. x-projection via small MFMA (C=0, A_x nonzero only
// quad0 k=0,1).
//
// Activation math (R6/R7, verified): pre-acts pre-scaled (i,f,o: log2e;
// g: 2log2e, folded into A). Cell kept in 2log2e domain. Paired rcp at
// both sites (R=rcp(Da*Db); 1/Da=R*Db). c' clamp 40 keeps paired products
// finite (tanh(40/2L2)=1-2e-12 == fp32 1.0, no output change).
__global__ __launch_bounds__(128, 2)
void lstm_fused(const float* __restrict__ x,
                const float* __restrict__ W_ih,
                const float* __restrict__ W_hh,
                const float* __restrict__ b_ih,
                const float* __restrict__ b_hh,
                const float* __restrict__ W_fc,
                const float* __restrict__ b_fc,
                float* __restrict__ out)
{
    __shared__ _Float16 sH[2][2][16 * HS];    // [tile][dbuf]: h[seq][unit] fp16
    __shared__ float    sXT[2][SEQ_LEN * 16]; // [tile]: x transposed [t][seq]

    const int tid  = threadIdx.x;
    const int wave = tid >> 6;
    const int lane = tid & 63;
    const int col  = lane & 15;
    const int quad = lane >> 4;
    const int seqBase = blockIdx.x << 5;   // 32 sequences per block

    // ---- stage x transposed (R1 loop, per tile)
    #pragma unroll
    for (int tb = 0; tb < 2; ++tb) {
        for (int i = tid; i < SEQ_LEN * 16; i += 128) {
            const int s = i & 15;
            const int t = i >> 4;
            sXT[tb][t * 16 + s] = x[(size_t)(seqBase + tb * 16 + s) * SEQ_LEN + t];
        }
    }
    // ---- zero all h buffers (h0 = 0)
    for (int i = tid; i < 2 * 2 * 16 * HS; i += 128)
        ((_Float16*)sH)[i] = (_Float16)0.0f;

    // ---- W_hh rows as resident fp16 A-fragments, pre-scaled (i,f,o: log2e;
    // g: 2log2e). Shared by both tiles. A[m=col][k=quad*8+j]. (R1 verbatim.)
    h8 Aw[8][2];
    axv_t Ax[8];
    #pragma unroll
    for (int gi = 0; gi < 4; ++gi) {
        const float scale = (gi == 2) ? LOG2E2 : LOG2E;
        #pragma unroll
        for (int d = 0; d < 2; ++d) {
            const int tt = gi * 2 + d;
            const int n  = (gi * 4 + 2 * wave + d) * 16 + col;
            axv_t axf = {};
            if (quad == 0) {
                axf[0] = (_Float16)(W_ih[n] * scale);
                axf[1] = (_Float16)((b_ih[n] + b_hh[n]) * scale);
            }
            Ax[tt] = axf;
            #pragma unroll
            for (int kf = 0; kf < 2; ++kf) {
                const float* wp = W_hh + n * HID + kf * 32 + quad * 8;
                f4 lo = *(const f4*)wp;
                f4 hi = *(const f4*)(wp + 4);
                h8 b;
                b[0] = (_Float16)(lo[0] * scale); b[1] = (_Float16)(lo[1] * scale);
                b[2] = (_Float16)(lo[2] * scale); b[3] = (_Float16)(lo[3] * scale);
                b[4] = (_Float16)(hi[0] * scale); b[5] = (_Float16)(hi[1] * scale);
                b[6] = (_Float16)(hi[2] * scale); b[7] = (_Float16)(hi[3] * scale);
                Aw[tt][kf] = b;
            }
        }
    }

    const f4 z4 = {0.0f, 0.0f, 0.0f, 0.0f};

    // cell state (2log2e domain), [tile][d][r] — compile-time indices only
    float c[2][2][4];
    #pragma unroll
    for (int tb = 0; tb < 2; ++tb)
        #pragma unroll
        for (int d = 0; d < 2; ++d)
            #pragma unroll
            for (int r = 0; r < 4; ++r) c[tb][d][r] = 0.0f;

    __syncthreads();

    for (int t = 0; t < SEQ_LEN; ++t) {
        // per-tile B fragments (R1 expressions with [tb])
        h8 Bh0[2], Bh1[2];
        axv_t bx[2];
        #pragma unroll
        for (int tb = 0; tb < 2; ++tb) {
            const _Float16* hb = sH[tb][t & 1];
            axv_t bxv = {};
            bxv[0] = (_Float16)sXT[tb][t * 16 + col];
            bxv[1] = (_Float16)1.0f;
            bx[tb]  = bxv;
            Bh0[tb] = *(const h8*)(hb + col * HS + quad * 8);
            Bh1[tb] = *(const h8*)(hb + col * HS + 32 + quad * 8);
        }

        #pragma unroll
        for (int d = 0; d < 2; ++d) {
            f4 acc[2][4];
            #pragma unroll
            for (int gi = 0; gi < 4; ++gi) {
                const int tt = gi * 2 + d;
                #pragma unroll
                for (int tb = 0; tb < 2; ++tb) {
                    f4 a = XMFMA(Ax[tt], bx[tb], z4);
                    a = WMFMA(Aw[tt][0], Bh0[tb], a);
                    a = WMFMA(Aw[tt][1], Bh1[tb], a);
                    acc[tb][gi] = a;
                }
            }
            // paired-rcp activations (R1 verbatim, with [tb])
            #pragma unroll
            for (int tb = 0; tb < 2; ++tb) {
                h4 hv;
                #pragma unroll
                for (int rp = 0; rp < 2; ++rp) {
                    const int r0 = rp * 2, r1 = r0 + 1;
                    float EiA = EXP2(-acc[tb][0][r0]);
                    float EfA = EXP2(-acc[tb][1][r0]);
                    float EgA = EXP2( acc[tb][2][r0]);
                    float EoA = EXP2(-acc[tb][3][r0]);
                    float EiB = EXP2(-acc[tb][0][r1]);
                    float EfB = EXP2(-acc[tb][1][r1]);
                    float EgB = EXP2( acc[tb][2][r1]);
                    float EoB = EXP2(-acc[tb][3][r1]);
                    float piA = 1.0f + EiA, pfA = 1.0f + EfA;
                    float pgA = 1.0f + EgA, poA = 1.0f + EoA;
                    float piB = 1.0f + EiB, pfB = 1.0f + EfB;
                    float pgB = 1.0f + EgB, poB = 1.0f + EoB;
                    float t1A = piA * pgA,  t1B = piB * pgB;
                    float DA  = pfA * t1A,  DB  = pfB * t1B;
                    float vA  = fmaf(EgA, pfA, -pfA) * LOG2E2;
                    float vB  = fmaf(EgB, pfB, -pfB) * LOG2E2;
                    float numA = fmaf(c[tb][d][r0], t1A, vA);
                    float numB = fmaf(c[tb][d][r1], t1B, vB);
                    float R   = RCP(DA * DB);
                    float cnA = fminf(numA * (R * DB), 40.0f);
                    float cnB = fminf(numB * (R * DA), 40.0f);
                    c[tb][d][r0] = cnA;
                    c[tb][d][r1] = cnB;
                    float EcA = EXP2(cnA), EcB = EXP2(cnB);
                    float DhA = fmaf(poA, EcA, poA);
                    float DhB = fmaf(poB, EcB, poB);
                    float R2  = RCP(DhA * DhB);
                    float rhA = R2 * DhB,  rhB = R2 * DhA;
                    hv[r0] = (_Float16)fmaf(EcA, rhA, -rhA);
                    hv[r1] = (_Float16)fmaf(EcB, rhB, -rhB);
                }
                *(h4*)(sH[tb][(t + 1) & 1] + col * HS + 32 * wave + 16 * d + quad * 4) = hv;
            }
        }
        __syncthreads();
    }

    // ---- epilogue: R1's verified mapping, looped over tiles.
    // Final h is in sH[tb][0] (t=50 even), layout h[seq][unit] stride HS.
    if (lane < 24) {
        const int sl = wave * 8 + lane / 3;  // sequence within tile
        const int nc = lane % 3;             // class
        #pragma unroll
        for (int tb = 0; tb < 2; ++tb) {
            const _Float16* hp = sH[tb][0] + sl * HS;
            float a = b_fc[nc];
            #pragma unroll
            for (int u = 0; u < HID; ++u)
                a = fmaf((float)hp[u], W_fc[nc * HID + u], a);
            out[(size_t)(seqBase + tb * 16 + sl) * 3 + nc] = a;
        }
    }
}

extern "C" void kernel_launch(void* const* d_in, const int* in_sizes, int n_in,
                              void* d_out, int out_size, void* d_ws, size_t ws_size,
                              hipStream_t stream) {
    const float* x    = (const float*)d_in[0];
    const float* W_ih = (const float*)d_in[1];
    const float* W_hh = (const float*)d_in[2];
    const float* b_ih = (const float*)d_in[3];
    const float* b_hh = (const float*)d_in[4];
    const float* W_fc = (const float*)d_in[5];
    const float* b_fc = (const float*)d_in[6];
    float* out = (float*)d_out;

    const int nSeq   = in_sizes[0] / SEQ_LEN;  // 512000
    const int blocks = nSeq / 32;              // 16000

    hipLaunchKernelGGL(lstm_fused, dim3(blocks), dim3(128), 0, stream,
                       x, W_ih, W_hh, b_ih, b_hh, W_fc, b_fc, out);
}